// Round 1
// baseline (13999.136 us; speedup 1.0000x reference)
//
#include <hip/hip_runtime.h>
#include <math.h>

#define LL 256
#define BB 256
#define HH 256
#define CC 16
#define YY 32
#define HC (HH*CC)     // 4096
#define NSTEP (LL-1)   // 255

// ---------------------------------------------------------------------------
// init: z_seq[0] = h0;  d[k,b,c] = dnode[b,k,c]  (tau==0 since ts==arange(L))
//   c==0: ts diff (==1);  c>=1: us[kk,b,c-1]-us[kk-1,b,c-1], kk=max(k,1)
// ---------------------------------------------------------------------------
__global__ void k_init(const float* __restrict__ ts, const float* __restrict__ us,
                       const float* __restrict__ h0, float* __restrict__ zseq,
                       float* __restrict__ darr) {
    int i = blockIdx.x * blockDim.x + threadIdx.x;
    if (i < BB * HH) zseq[i] = h0[i];
    int nd = NSTEP * BB * CC;
    int stride = gridDim.x * blockDim.x;
    for (int j = i; j < nd; j += stride) {
        int k  = j / (BB * CC);
        int rb = j % (BB * CC);
        int b = rb / CC, c = rb % CC;
        int kk = (k < 1) ? 1 : k;
        float v;
        if (c == 0) {
            v = ts[kk * BB] - ts[(kk - 1) * BB];
        } else {
            int m = c - 1;
            v = us[kk * BB * (CC - 1) + b * (CC - 1) + m]
              - us[(kk - 1) * BB * (CC - 1) + b * (CC - 1) + m];
        }
        darr[k * BB * CC + b * CC + c] = v;
    }
}

// ---------------------------------------------------------------------------
// hid = relu(z @ W1 + b1)      grid: (B/8, H/64), block 256
// ---------------------------------------------------------------------------
__global__ void k_hid(const float* __restrict__ z, const float* __restrict__ W1,
                      const float* __restrict__ b1, float* __restrict__ hid) {
    __shared__ float zt[8][HH];      // 8 KB
    int b0 = blockIdx.x * 8;
    int h0 = blockIdx.y * 64;
    int t  = threadIdx.x;
    {
        const float4* src = (const float4*)(z + (size_t)b0 * HH);
        float4* dst = (float4*)(&zt[0][0]);
        for (int i = t; i < 8 * HH / 4; i += 256) dst[i] = src[i];
    }
    __syncthreads();
    int hl = t & 63;
    int bs = t >> 6;                 // 0..3
    int h  = h0 + hl;
    float acc0 = 0.f, acc1 = 0.f;
    #pragma unroll 4
    for (int j = 0; j < HH; j++) {
        float w = W1[j * HH + h];
        acc0 += zt[bs][j]     * w;
        acc1 += zt[bs + 4][j] * w;
    }
    float bias = b1[h];
    hid[(size_t)(b0 + bs) * HH + h]     = fmaxf(acc0 + bias, 0.f);
    hid[(size_t)(b0 + bs + 4) * HH + h] = fmaxf(acc1 + bias, 0.f);
}

// ---------------------------------------------------------------------------
// step: g = hid @ W2 + b2;  dz[b,h] = sum_c tanh(g[b,h*16+c]) * d[k,b,c];
//       z_{k+1} = z_k + dz          grid: (B/64, HC/64) = 4 x 64, block 256
// thread owns one (b, h-group): 16 c-columns -> epilogue reduction is local
// ---------------------------------------------------------------------------
__global__ void k_step(const float* __restrict__ hid, const float* __restrict__ W2,
                       const float* __restrict__ b2, const float* __restrict__ darr,
                       const float* __restrict__ zk, float* __restrict__ zk1, int k) {
    __shared__ float w2t[32][64];    // 8 KB
    __shared__ float ht[32][65];     // 8.3 KB (+1 pad: conflict-free transpose)
    int b0 = blockIdx.x * 64;
    int n0 = blockIdx.y * 64;
    int t  = threadIdx.x;
    int nq = t & 3;                  // h-group within tile (4 groups of 16 cols)
    int bq = t >> 2;                 // 0..63  batch row within tile
    float acc[16];
    #pragma unroll
    for (int c = 0; c < 16; c++) acc[c] = 0.f;

    for (int jc = 0; jc < HH; jc += 32) {
        // stage W2[jc..jc+31][n0..n0+63]  (512 float4, 2/thread, coalesced)
        for (int i = t; i < 512; i += 256) {
            int r  = i >> 4;
            int cc = (i & 15) << 2;
            *(float4*)&w2t[r][cc] = *(const float4*)&W2[(size_t)(jc + r) * HC + n0 + cc];
        }
        // stage hid transposed: ht[j][b_local]
        for (int i = t; i < 512; i += 256) {
            int bl = i >> 3;
            int j4 = (i & 7) << 2;
            float4 v = *(const float4*)&hid[(size_t)(b0 + bl) * HH + jc + j4];
            ht[j4 + 0][bl] = v.x; ht[j4 + 1][bl] = v.y;
            ht[j4 + 2][bl] = v.z; ht[j4 + 3][bl] = v.w;
        }
        __syncthreads();
        #pragma unroll 8
        for (int r = 0; r < 32; r++) {
            float hv = ht[r][bq];
            const float4* wp = (const float4*)&w2t[r][nq * 16];
            float4 w0 = wp[0], w1 = wp[1], w2v = wp[2], w3 = wp[3];
            acc[0]  += hv * w0.x;  acc[1]  += hv * w0.y;
            acc[2]  += hv * w0.z;  acc[3]  += hv * w0.w;
            acc[4]  += hv * w1.x;  acc[5]  += hv * w1.y;
            acc[6]  += hv * w1.z;  acc[7]  += hv * w1.w;
            acc[8]  += hv * w2v.x; acc[9]  += hv * w2v.y;
            acc[10] += hv * w2v.z; acc[11] += hv * w2v.w;
            acc[12] += hv * w3.x;  acc[13] += hv * w3.y;
            acc[14] += hv * w3.z;  acc[15] += hv * w3.w;
        }
        __syncthreads();
    }
    int b = b0 + bq;
    int h = (n0 >> 4) + nq;          // global h = (n0 + nq*16)/16
    const float* dv = &darr[(size_t)k * BB * CC + b * CC];
    float s = 0.f;
    #pragma unroll
    for (int c = 0; c < 16; c++) {
        float g = acc[c] + b2[n0 + nq * 16 + c];
        s += tanhf(g) * dv[c];
    }
    zk1[(size_t)b * HH + h] = zk[(size_t)b * HH + h] + s;   // dt == 1
}

// ---------------------------------------------------------------------------
// out = tanh(z_seq @ dW1 + db1) @ dW2 + db2     grid: L*B/16 = 4096, block 256
// ---------------------------------------------------------------------------
__global__ void k_out(const float* __restrict__ zseq, const float* __restrict__ dW1,
                      const float* __restrict__ db1, const float* __restrict__ dW2,
                      const float* __restrict__ db2, float* __restrict__ out) {
    __shared__ float zt[16][HH];       // 16 KB
    __shared__ float act[16][2 * HH];  // 32 KB
    int r0 = blockIdx.x * 16;          // global row = l*B + b
    int t  = threadIdx.x;
    {
        const float4* src = (const float4*)(zseq + (size_t)r0 * HH);
        float4* dst = (float4*)&zt[0][0];
        for (int i = t; i < 1024; i += 256) dst[i] = src[i];
    }
    __syncthreads();
    {   // phase 1: act = tanh(z @ dW1 + db1), 512 cols
        int c0  = (t & 127) * 4;       // 4 consecutive cols
        int rr0 = (t >> 7) * 8;        // 8 rows
        float a[8][4];
        #pragma unroll
        for (int i = 0; i < 8; i++)
            #pragma unroll
            for (int q = 0; q < 4; q++) a[i][q] = 0.f;
        for (int j = 0; j < HH; j++) {
            float4 w = *(const float4*)&dW1[(size_t)j * 2 * HH + c0];
            #pragma unroll
            for (int i = 0; i < 8; i++) {
                float zv = zt[rr0 + i][j];
                a[i][0] += zv * w.x; a[i][1] += zv * w.y;
                a[i][2] += zv * w.z; a[i][3] += zv * w.w;
            }
        }
        float4 bias = *(const float4*)&db1[c0];
        #pragma unroll
        for (int i = 0; i < 8; i++) {
            act[rr0 + i][c0 + 0] = tanhf(a[i][0] + bias.x);
            act[rr0 + i][c0 + 1] = tanhf(a[i][1] + bias.y);
            act[rr0 + i][c0 + 2] = tanhf(a[i][2] + bias.z);
            act[rr0 + i][c0 + 3] = tanhf(a[i][3] + bias.w);
        }
    }
    __syncthreads();
    {   // phase 2: out = act @ dW2 + db2
        int rl = t >> 4;               // 0..15
        int y2 = t & 15;               // column pair
        float o0 = 0.f, o1 = 0.f;
        #pragma unroll 4
        for (int j = 0; j < 2 * HH; j++) {
            float av = act[rl][j];
            float2 w = *(const float2*)&dW2[j * YY + y2 * 2];
            o0 += av * w.x; o1 += av * w.y;
        }
        float2 bias = *(const float2*)&db2[y2 * 2];
        out[(size_t)(r0 + rl) * YY + y2 * 2]     = o0 + bias.x;
        out[(size_t)(r0 + rl) * YY + y2 * 2 + 1] = o1 + bias.y;
    }
}

// ---------------------------------------------------------------------------
extern "C" void kernel_launch(void* const* d_in, const int* in_sizes, int n_in,
                              void* d_out, int out_size, void* d_ws, size_t ws_size,
                              hipStream_t stream) {
    const float* ts  = (const float*)d_in[0];
    const float* us  = (const float*)d_in[1];
    const float* h0  = (const float*)d_in[2];
    const float* W1  = (const float*)d_in[3];
    const float* b1  = (const float*)d_in[4];
    const float* W2  = (const float*)d_in[5];
    const float* b2  = (const float*)d_in[6];
    const float* dW1 = (const float*)d_in[7];
    const float* db1 = (const float*)d_in[8];
    const float* dW2 = (const float*)d_in[9];
    const float* db2 = (const float*)d_in[10];
    float* out = (float*)d_out;

    float* zseq = (float*)d_ws;                        // L*B*H   = 64 MB
    float* darr = zseq + (size_t)LL * BB * HH;         // L*B*C   =  4 MB
    float* hid  = darr + (size_t)LL * BB * CC;         // B*H     = 256 KB

    k_init<<<4096, 256, 0, stream>>>(ts, us, h0, zseq, darr);
    for (int k = 0; k < NSTEP; k++) {
        const float* zk = zseq + (size_t)k * BB * HH;
        float*      zk1 = zseq + (size_t)(k + 1) * BB * HH;
        k_hid<<<dim3(BB / 8, HH / 64), 256, 0, stream>>>(zk, W1, b1, hid);
        k_step<<<dim3(BB / 64, HC / 64), 256, 0, stream>>>(hid, W2, b2, darr, zk, zk1, k);
    }
    k_out<<<LL * BB / 16, 256, 0, stream>>>(zseq, dW1, db1, dW2, db2, out);
}